// Round 4
// baseline (584.216 us; speedup 1.0000x reference)
//
#include <hip/hip_runtime.h>

#define DIM 128

// ---------------- degree count ----------------
__global__ __launch_bounds__(256) void k_count(const int* __restrict__ dst,
                                               int* __restrict__ deg, int E) {
    int t = blockIdx.x * 256 + threadIdx.x;
    if (t < E) atomicAdd(&deg[dst[t]], 1);
}

__global__ __launch_bounds__(256) void k_dinv(const int* __restrict__ deg,
                                              float* __restrict__ dinv, int N) {
    int t = blockIdx.x * 256 + threadIdx.x;
    if (t < N) dinv[t] = rsqrtf((float)(deg[t] + 1));  // +1 = self-loop
}

// ---------------- single-block exclusive scan -> rowptr, cursor ----------------
__global__ __launch_bounds__(1024) void k_scan(const int* __restrict__ deg,
                                               int* __restrict__ rowptr,
                                               int* __restrict__ cursor, int N) {
    int t = threadIdx.x;
    int chunk = (N + 1023) >> 10;
    int s0 = t * chunk, s1 = min(s0 + chunk, N);
    int sum = 0;
    for (int i = s0; i < s1; ++i) sum += deg[i];
    __shared__ int ps[1024];
    ps[t] = sum;
    __syncthreads();
    for (int off = 1; off < 1024; off <<= 1) {
        int v = (t >= off) ? ps[t - off] : 0;
        __syncthreads();
        ps[t] += v;
        __syncthreads();
    }
    int base = (t == 0) ? 0 : ps[t - 1];
    for (int i = s0; i < s1; ++i) { rowptr[i] = base; cursor[i] = base; base += deg[i]; }
    if (t == 0) rowptr[N] = ps[1023];
}

// ---------------- CSR fill: {src, weight} per edge, grouped by dst ----------------
__global__ __launch_bounds__(256) void k_fill(const int* __restrict__ src,
                                              const int* __restrict__ dst,
                                              const float* __restrict__ dinv,
                                              int* __restrict__ cursor,
                                              int2* __restrict__ csr, int E) {
    int e = blockIdx.x * 256 + threadIdx.x;
    if (e >= E) return;
    int s = src[e], d = dst[e];
    int p = atomicAdd(&cursor[d], 1);
    float w = dinv[s] * dinv[d];
    csr[p] = make_int2(s, __float_as_int(w));
}

// ---------------- dense GEMM: H = (cvec +) f(X) @ W ----------------
template<bool RELU_IN, bool ADD_C>
__global__ __launch_bounds__(256) void k_gemm(const float* __restrict__ X,
                                              const float* __restrict__ W,
                                              const float* __restrict__ Cvec,
                                              float* __restrict__ H, int n) {
    __shared__ float sW[64 * DIM];   // 32 KB, one K-chunk of W [k2][j]
    __shared__ float sX[32][DIM];    // 16 KB
    const int jq = threadIdx.x & 31;
    const int rr = threadIdx.x >> 5;   // 0..7
    float4 cj = ADD_C ? ((const float4*)Cvec)[jq] : make_float4(0.f, 0.f, 0.f, 0.f);
    for (int base = blockIdx.x * 32; base < n; base += gridDim.x * 32) {
        __syncthreads();
        for (int u = threadIdx.x; u < 32 * 32; u += 256) {
            int row = u >> 5, c4 = u & 31;
            int gi = base + row;
            float4 v = make_float4(0.f, 0.f, 0.f, 0.f);
            if (gi < n) v = ((const float4*)(X + (size_t)gi * DIM))[c4];
            if (RELU_IN) {
                v.x = fmaxf(v.x, 0.f); v.y = fmaxf(v.y, 0.f);
                v.z = fmaxf(v.z, 0.f); v.w = fmaxf(v.w, 0.f);
            }
            ((float4*)sX[row])[c4] = v;
        }
        float4 a0 = cj, a1 = cj, a2 = cj, a3 = cj;
        for (int kk = 0; kk < DIM; kk += 64) {
            __syncthreads();
            for (int u = threadIdx.x; u < 64 * 32; u += 256)
                ((float4*)sW)[u] = ((const float4*)(W + (size_t)kk * DIM))[u];
            __syncthreads();
            #pragma unroll 8
            for (int k2 = 0; k2 < 64; ++k2) {
                int k = kk + k2;
                float4 w4 = ((const float4*)sW)[k2 * 32 + jq];
                float x0 = sX[rr * 4 + 0][k], x1 = sX[rr * 4 + 1][k];
                float x2 = sX[rr * 4 + 2][k], x3 = sX[rr * 4 + 3][k];
                a0.x = fmaf(x0, w4.x, a0.x); a0.y = fmaf(x0, w4.y, a0.y);
                a0.z = fmaf(x0, w4.z, a0.z); a0.w = fmaf(x0, w4.w, a0.w);
                a1.x = fmaf(x1, w4.x, a1.x); a1.y = fmaf(x1, w4.y, a1.y);
                a1.z = fmaf(x1, w4.z, a1.z); a1.w = fmaf(x1, w4.w, a1.w);
                a2.x = fmaf(x2, w4.x, a2.x); a2.y = fmaf(x2, w4.y, a2.y);
                a2.z = fmaf(x2, w4.z, a2.z); a2.w = fmaf(x2, w4.w, a2.w);
                a3.x = fmaf(x3, w4.x, a3.x); a3.y = fmaf(x3, w4.y, a3.y);
                a3.z = fmaf(x3, w4.z, a3.z); a3.w = fmaf(x3, w4.w, a3.w);
            }
        }
        int i0 = base + rr * 4;
        if (i0 + 0 < n) ((float4*)(H + (size_t)(i0 + 0) * DIM))[jq] = a0;
        if (i0 + 1 < n) ((float4*)(H + (size_t)(i0 + 1) * DIM))[jq] = a1;
        if (i0 + 2 < n) ((float4*)(H + (size_t)(i0 + 2) * DIM))[jq] = a2;
        if (i0 + 3 < n) ((float4*)(H + (size_t)(i0 + 3) * DIM))[jq] = a3;
    }
}

// ---------------- c[j] = sum_k relu(posts[root][k]) * W2[k][j] ----------------
__global__ __launch_bounds__(DIM) void k_cvec(const float* __restrict__ posts,
                                              const int* __restrict__ root,
                                              const float* __restrict__ W2,
                                              float* __restrict__ cvec) {
    int j = threadIdx.x;
    const float* xr = posts + (size_t)root[0] * DIM;
    float acc = 0.0f;
    #pragma unroll 8
    for (int k = 0; k < DIM; ++k)
        acc = fmaf(fmaxf(xr[k], 0.0f), W2[k * DIM + j], acc);
    cvec[j] = acc;
}

// 8-edge-deep accumulate of h rows into (ax,ay,az,aw) for lane-quad q.
// Main loop: 8 independent row loads in flight. Tail: one predicated 8-batch.
__device__ __forceinline__ void edge_accum(const int2* __restrict__ csr,
                                           int beg, int end, int q,
                                           const float* __restrict__ h,
                                           float& ax, float& ay, float& az, float& aw) {
    int e = beg;
    for (; e + 8 <= end; e += 8) {
        int2 ee[8];
        float4 vv[8];
        #pragma unroll
        for (int u = 0; u < 8; ++u) ee[u] = csr[e + u];
        #pragma unroll
        for (int u = 0; u < 8; ++u)
            vv[u] = ((const float4*)(h + (size_t)ee[u].x * DIM))[q];
        #pragma unroll
        for (int u = 0; u < 8; ++u) {
            float w = __int_as_float(ee[u].y);
            ax = fmaf(vv[u].x, w, ax); ay = fmaf(vv[u].y, w, ay);
            az = fmaf(vv[u].z, w, az); aw = fmaf(vv[u].w, w, aw);
        }
    }
    int rem = end - e;
    if (rem > 0) {
        int2 ee[8];
        float4 vv[8];
        #pragma unroll
        for (int u = 0; u < 8; ++u)
            ee[u] = (u < rem) ? csr[e + u] : make_int2(0, 0);
        #pragma unroll
        for (int u = 0; u < 8; ++u)
            vv[u] = (u < rem) ? ((const float4*)(h + (size_t)ee[u].x * DIM))[q]
                              : make_float4(0.f, 0.f, 0.f, 0.f);
        #pragma unroll
        for (int u = 0; u < 8; ++u) {
            float w = __int_as_float(ee[u].y);
            ax = fmaf(vv[u].x, w, ax); ay = fmaf(vv[u].y, w, ay);
            az = fmaf(vv[u].z, w, az); aw = fmaf(vv[u].w, w, aw);
        }
    }
}

// ---------------- gather layer 1: conv1 = A_norm @ h + self + b1 (grid-stride) ----------------
__global__ __launch_bounds__(256) void k_gather1(const int2* __restrict__ csr,
                                                 const int* __restrict__ rowptr,
                                                 const float* __restrict__ dinv,
                                                 const float* __restrict__ h,
                                                 const float* __restrict__ b1,
                                                 const int* __restrict__ root,
                                                 float* __restrict__ conv1,
                                                 float* __restrict__ out, int N) {
    int q = threadIdx.x & 31;
    int g = threadIdx.x >> 5;   // 0..7
    float4 bv = ((const float4*)b1)[q];
    int rt = root[0];
    for (int d = blockIdx.x * 8 + g; d < N; d += gridDim.x * 8) {
        int beg = rowptr[d], end = rowptr[d + 1];
        float ax = 0.f, ay = 0.f, az = 0.f, aw = 0.f;
        edge_accum(csr, beg, end, q, h, ax, ay, az, aw);
        float di = dinv[d], sl = di * di;
        float4 hv = ((const float4*)(h + (size_t)d * DIM))[q];
        float4 r;
        r.x = fmaf(hv.x, sl, ax) + bv.x;
        r.y = fmaf(hv.y, sl, ay) + bv.y;
        r.z = fmaf(hv.z, sl, az) + bv.z;
        r.w = fmaf(hv.w, sl, aw) + bv.w;
        ((float4*)(conv1 + (size_t)d * DIM))[q] = r;
        if (d == rt) ((float4*)out)[q] = r;   // conv1_root (no relu)
    }
}

// ---------------- gather layer 2 + relu + fused column-mean (grid-stride) ----------------
__global__ __launch_bounds__(256) void k_gather2(const int2* __restrict__ csr,
                                                 const int* __restrict__ rowptr,
                                                 const float* __restrict__ dinv,
                                                 const float* __restrict__ h,
                                                 const float* __restrict__ b2,
                                                 float* __restrict__ meanacc, int N) {
    int q = threadIdx.x & 31;
    int g = threadIdx.x >> 5;   // 0..7
    float4 bv = ((const float4*)b2)[q];
    float sx = 0.f, sy = 0.f, sz = 0.f, sw = 0.f;  // running column sum
    for (int d = blockIdx.x * 8 + g; d < N; d += gridDim.x * 8) {
        int beg = rowptr[d], end = rowptr[d + 1];
        float ax = 0.f, ay = 0.f, az = 0.f, aw = 0.f;
        edge_accum(csr, beg, end, q, h, ax, ay, az, aw);
        float di = dinv[d], sl = di * di;
        float4 hv = ((const float4*)(h + (size_t)d * DIM))[q];
        sx += fmaxf(fmaf(hv.x, sl, ax) + bv.x, 0.f);
        sy += fmaxf(fmaf(hv.y, sl, ay) + bv.y, 0.f);
        sz += fmaxf(fmaf(hv.z, sl, az) + bv.z, 0.f);
        sw += fmaxf(fmaf(hv.w, sl, aw) + bv.w, 0.f);
    }
    __shared__ float4 sp[256];
    sp[threadIdx.x] = make_float4(sx, sy, sz, sw);
    __syncthreads();
    if (threadIdx.x < 32) {
        float4 s = sp[threadIdx.x];
        #pragma unroll
        for (int gg = 1; gg < 8; ++gg) {
            float4 o = sp[gg * 32 + threadIdx.x];
            s.x += o.x; s.y += o.y; s.z += o.z; s.w += o.w;
        }
        unsafeAtomicAdd(&meanacc[q * 4 + 0], s.x);
        unsafeAtomicAdd(&meanacc[q * 4 + 1], s.y);
        unsafeAtomicAdd(&meanacc[q * 4 + 2], s.z);
        unsafeAtomicAdd(&meanacc[q * 4 + 3], s.w);
    }
}

__global__ __launch_bounds__(DIM) void k_reduce(const float* __restrict__ meanacc,
                                                float* __restrict__ out, int N) {
    int j = threadIdx.x;
    out[DIM + j] = meanacc[j] / (float)N;
}

extern "C" void kernel_launch(void* const* d_in, const int* in_sizes, int n_in,
                              void* d_out, int out_size, void* d_ws, size_t ws_size,
                              hipStream_t stream) {
    const float* posts = (const float*)d_in[0];
    const int*   eidx  = (const int*)d_in[1];
    const int*   root  = (const int*)d_in[2];
    const float* W1    = (const float*)d_in[3];
    const float* b1    = (const float*)d_in[4];
    const float* W2    = (const float*)d_in[5];
    const float* b2    = (const float*)d_in[6];
    float* out = (float*)d_out;

    int N = in_sizes[0] / DIM;
    int E = in_sizes[1] / 2;
    const int* src = eidx;
    const int* dst = eidx + E;

    char* ws = (char*)d_ws;
    size_t off = 0;
    auto alloc = [&](size_t bytes) {
        void* p = ws + off;
        off += (bytes + 511) & ~(size_t)511;
        return p;
    };
    int*   deg     = (int*)  alloc((size_t)N * 4);
    int*   rowptr  = (int*)  alloc((size_t)(N + 1) * 4);
    int*   cursor  = (int*)  alloc((size_t)N * 4);
    float* dinv    = (float*)alloc((size_t)N * 4);
    float* cvec    = (float*)alloc(DIM * 4);
    float* meanacc = (float*)alloc(DIM * 4);
    int2*  csr     = (int2*) alloc((size_t)E * 8);
    float* h       = (float*)alloc((size_t)N * DIM * 4);   // h1, then h2
    float* conv1   = (float*)alloc((size_t)N * DIM * 4);   // conv1_out

    hipMemsetAsync(deg, 0, (size_t)N * 4, stream);
    hipMemsetAsync(meanacc, 0, DIM * 4, stream);

    // CSR build (once, shared by both layers)
    k_count<<<(E + 255) / 256, 256, 0, stream>>>(dst, deg, E);
    k_scan<<<1, 1024, 0, stream>>>(deg, rowptr, cursor, N);
    k_dinv<<<(N + 255) / 256, 256, 0, stream>>>(deg, dinv, N);
    k_fill<<<(E + 255) / 256, 256, 0, stream>>>(src, dst, dinv, cursor, csr, E);

    // layer 1
    k_gemm<false, false><<<512, 256, 0, stream>>>(posts, W1, nullptr, h, N);
    k_gather1<<<2048, 256, 0, stream>>>(csr, rowptr, dinv, h, b1, root, conv1, out, N);

    // layer 2: h2 = cvec + relu(conv1) @ W2[128:], cvec = relu(post_root) @ W2[:128]
    k_cvec<<<1, DIM, 0, stream>>>(posts, root, W2, cvec);
    k_gemm<true, true><<<512, 256, 0, stream>>>(conv1, W2 + DIM * DIM, cvec, h, N);
    k_gather2<<<2048, 256, 0, stream>>>(csr, rowptr, dinv, h, b2, meanacc, N);
    k_reduce<<<1, DIM, 0, stream>>>(meanacc, out, N);
}

// Round 5
// 539.372 us; speedup vs baseline: 1.0831x; 1.0831x over previous
//
#include <hip/hip_runtime.h>

#define DIM 128
typedef unsigned int uint;
typedef unsigned short ushort;

// bf16 pack/unpack (RNE)
__device__ __forceinline__ ushort f2bf(float x) {
    uint u = __float_as_uint(x);
    u = u + 0x7FFFu + ((u >> 16) & 1u);
    return (ushort)(u >> 16);
}
__device__ __forceinline__ uint pack2(float a, float b) {
    return (uint)f2bf(a) | ((uint)f2bf(b) << 16);
}

// ---------------- degree count ----------------
__global__ __launch_bounds__(256) void k_count(const int* __restrict__ dst,
                                               int* __restrict__ deg, int E) {
    int t = blockIdx.x * 256 + threadIdx.x;
    if (t < E) atomicAdd(&deg[dst[t]], 1);
}

__global__ __launch_bounds__(256) void k_dinv(const int* __restrict__ deg,
                                              float* __restrict__ dinv, int N) {
    int t = blockIdx.x * 256 + threadIdx.x;
    if (t < N) dinv[t] = rsqrtf((float)(deg[t] + 1));  // +1 = self-loop
}

// ---------------- single-block exclusive scan -> rowptr, cursor ----------------
__global__ __launch_bounds__(1024) void k_scan(const int* __restrict__ deg,
                                               int* __restrict__ rowptr,
                                               int* __restrict__ cursor, int N) {
    int t = threadIdx.x;
    int chunk = (N + 1023) >> 10;
    int s0 = t * chunk, s1 = min(s0 + chunk, N);
    int sum = 0;
    for (int i = s0; i < s1; ++i) sum += deg[i];
    __shared__ int ps[1024];
    ps[t] = sum;
    __syncthreads();
    for (int off = 1; off < 1024; off <<= 1) {
        int v = (t >= off) ? ps[t - off] : 0;
        __syncthreads();
        ps[t] += v;
        __syncthreads();
    }
    int base = (t == 0) ? 0 : ps[t - 1];
    for (int i = s0; i < s1; ++i) { rowptr[i] = base; cursor[i] = base; base += deg[i]; }
    if (t == 0) rowptr[N] = ps[1023];
}

// ---------------- CSR fill: {src, weight} per edge, grouped by dst ----------------
__global__ __launch_bounds__(256) void k_fill(const int* __restrict__ src,
                                              const int* __restrict__ dst,
                                              const float* __restrict__ dinv,
                                              int* __restrict__ cursor,
                                              int2* __restrict__ csr, int E) {
    int e = blockIdx.x * 256 + threadIdx.x;
    if (e >= E) return;
    int s = src[e], d = dst[e];
    int p = atomicAdd(&cursor[d], 1);
    float w = dinv[s] * dinv[d];
    csr[p] = make_int2(s, __float_as_int(w));
}

// ---------------- dense GEMM: H(bf16) = (cvec +) f(X) @ W ----------------
template<bool RELU_IN, bool ADD_C>
__global__ __launch_bounds__(256) void k_gemm(const float* __restrict__ X,
                                              const float* __restrict__ W,
                                              const float* __restrict__ Cvec,
                                              ushort* __restrict__ H, int n) {
    __shared__ float sW[64 * DIM];   // 32 KB, one K-chunk of W [k2][j]
    __shared__ float sX[32][DIM];    // 16 KB
    const int jq = threadIdx.x & 31;
    const int rr = threadIdx.x >> 5;   // 0..7
    float4 cj = ADD_C ? ((const float4*)Cvec)[jq] : make_float4(0.f, 0.f, 0.f, 0.f);
    for (int base = blockIdx.x * 32; base < n; base += gridDim.x * 32) {
        __syncthreads();
        for (int u = threadIdx.x; u < 32 * 32; u += 256) {
            int row = u >> 5, c4 = u & 31;
            int gi = base + row;
            float4 v = make_float4(0.f, 0.f, 0.f, 0.f);
            if (gi < n) v = ((const float4*)(X + (size_t)gi * DIM))[c4];
            if (RELU_IN) {
                v.x = fmaxf(v.x, 0.f); v.y = fmaxf(v.y, 0.f);
                v.z = fmaxf(v.z, 0.f); v.w = fmaxf(v.w, 0.f);
            }
            ((float4*)sX[row])[c4] = v;
        }
        float4 a0 = cj, a1 = cj, a2 = cj, a3 = cj;
        for (int kk = 0; kk < DIM; kk += 64) {
            __syncthreads();
            for (int u = threadIdx.x; u < 64 * 32; u += 256)
                ((float4*)sW)[u] = ((const float4*)(W + (size_t)kk * DIM))[u];
            __syncthreads();
            #pragma unroll 8
            for (int k2 = 0; k2 < 64; ++k2) {
                int k = kk + k2;
                float4 w4 = ((const float4*)sW)[k2 * 32 + jq];
                float x0 = sX[rr * 4 + 0][k], x1 = sX[rr * 4 + 1][k];
                float x2 = sX[rr * 4 + 2][k], x3 = sX[rr * 4 + 3][k];
                a0.x = fmaf(x0, w4.x, a0.x); a0.y = fmaf(x0, w4.y, a0.y);
                a0.z = fmaf(x0, w4.z, a0.z); a0.w = fmaf(x0, w4.w, a0.w);
                a1.x = fmaf(x1, w4.x, a1.x); a1.y = fmaf(x1, w4.y, a1.y);
                a1.z = fmaf(x1, w4.z, a1.z); a1.w = fmaf(x1, w4.w, a1.w);
                a2.x = fmaf(x2, w4.x, a2.x); a2.y = fmaf(x2, w4.y, a2.y);
                a2.z = fmaf(x2, w4.z, a2.z); a2.w = fmaf(x2, w4.w, a2.w);
                a3.x = fmaf(x3, w4.x, a3.x); a3.y = fmaf(x3, w4.y, a3.y);
                a3.z = fmaf(x3, w4.z, a3.z); a3.w = fmaf(x3, w4.w, a3.w);
            }
        }
        int i0 = base + rr * 4;
        if (i0 + 0 < n) ((uint2*)(H + (size_t)(i0 + 0) * DIM))[jq] =
            make_uint2(pack2(a0.x, a0.y), pack2(a0.z, a0.w));
        if (i0 + 1 < n) ((uint2*)(H + (size_t)(i0 + 1) * DIM))[jq] =
            make_uint2(pack2(a1.x, a1.y), pack2(a1.z, a1.w));
        if (i0 + 2 < n) ((uint2*)(H + (size_t)(i0 + 2) * DIM))[jq] =
            make_uint2(pack2(a2.x, a2.y), pack2(a2.z, a2.w));
        if (i0 + 3 < n) ((uint2*)(H + (size_t)(i0 + 3) * DIM))[jq] =
            make_uint2(pack2(a3.x, a3.y), pack2(a3.z, a3.w));
    }
}

// ---------------- c[j] = sum_k relu(posts[root][k]) * W2[k][j] ----------------
__global__ __launch_bounds__(DIM) void k_cvec(const float* __restrict__ posts,
                                              const int* __restrict__ root,
                                              const float* __restrict__ W2,
                                              float* __restrict__ cvec) {
    int j = threadIdx.x;
    const float* xr = posts + (size_t)root[0] * DIM;
    float acc = 0.0f;
    #pragma unroll 8
    for (int k = 0; k < DIM; ++k)
        acc = fmaf(fmaxf(xr[k], 0.0f), W2[k * DIM + j], acc);
    cvec[j] = acc;
}

// unpack uint2 (4 bf16) and fma into acc
__device__ __forceinline__ void bf4_fma(uint2 p, float w,
                                        float& ax, float& ay, float& az, float& aw) {
    ax = fmaf(__uint_as_float(p.x << 16), w, ax);
    ay = fmaf(__uint_as_float(p.x & 0xFFFF0000u), w, ay);
    az = fmaf(__uint_as_float(p.y << 16), w, az);
    aw = fmaf(__uint_as_float(p.y & 0xFFFF0000u), w, aw);
}

// 8-edge-deep accumulate of bf16 h rows into (ax..aw) for lane-quad q.
__device__ __forceinline__ void edge_accum(const int2* __restrict__ csr,
                                           int beg, int end, int q,
                                           const ushort* __restrict__ h,
                                           float& ax, float& ay, float& az, float& aw) {
    int e = beg;
    for (; e + 8 <= end; e += 8) {
        int2 ee[8];
        uint2 vv[8];
        #pragma unroll
        for (int u = 0; u < 8; ++u) ee[u] = csr[e + u];
        #pragma unroll
        for (int u = 0; u < 8; ++u)
            vv[u] = ((const uint2*)(h + (size_t)ee[u].x * DIM))[q];
        #pragma unroll
        for (int u = 0; u < 8; ++u)
            bf4_fma(vv[u], __int_as_float(ee[u].y), ax, ay, az, aw);
    }
    int rem = end - e;
    if (rem > 0) {
        int2 ee[8];
        uint2 vv[8];
        #pragma unroll
        for (int u = 0; u < 8; ++u)
            ee[u] = (u < rem) ? csr[e + u] : make_int2(0, 0);
        #pragma unroll
        for (int u = 0; u < 8; ++u)
            vv[u] = (u < rem) ? ((const uint2*)(h + (size_t)ee[u].x * DIM))[q]
                              : make_uint2(0u, 0u);
        #pragma unroll
        for (int u = 0; u < 8; ++u)
            bf4_fma(vv[u], __int_as_float(ee[u].y), ax, ay, az, aw);
    }
}

// ---------------- gather layer 1: conv1(f32) = A_norm @ h + self + b1 ----------------
__global__ __launch_bounds__(256) void k_gather1(const int2* __restrict__ csr,
                                                 const int* __restrict__ rowptr,
                                                 const float* __restrict__ dinv,
                                                 const ushort* __restrict__ h,
                                                 const float* __restrict__ b1,
                                                 const int* __restrict__ root,
                                                 float* __restrict__ conv1,
                                                 float* __restrict__ out, int N) {
    int q = threadIdx.x & 31;
    int g = threadIdx.x >> 5;   // 0..7
    float4 bv = ((const float4*)b1)[q];
    int rt = root[0];
    for (int d = blockIdx.x * 8 + g; d < N; d += gridDim.x * 8) {
        int beg = rowptr[d], end = rowptr[d + 1];
        float ax = 0.f, ay = 0.f, az = 0.f, aw = 0.f;
        edge_accum(csr, beg, end, q, h, ax, ay, az, aw);
        float di = dinv[d], sl = di * di;
        uint2 hv = ((const uint2*)(h + (size_t)d * DIM))[q];
        float4 r;
        r.x = fmaf(__uint_as_float(hv.x << 16), sl, ax) + bv.x;
        r.y = fmaf(__uint_as_float(hv.x & 0xFFFF0000u), sl, ay) + bv.y;
        r.z = fmaf(__uint_as_float(hv.y << 16), sl, az) + bv.z;
        r.w = fmaf(__uint_as_float(hv.y & 0xFFFF0000u), sl, aw) + bv.w;
        ((float4*)(conv1 + (size_t)d * DIM))[q] = r;
        if (d == rt) ((float4*)out)[q] = r;   // conv1_root (no relu)
    }
}

// ---------------- gather layer 2 + relu + fused column-mean (grid-stride) ----------------
__global__ __launch_bounds__(256) void k_gather2(const int2* __restrict__ csr,
                                                 const int* __restrict__ rowptr,
                                                 const float* __restrict__ dinv,
                                                 const ushort* __restrict__ h,
                                                 const float* __restrict__ b2,
                                                 float* __restrict__ meanacc, int N) {
    int q = threadIdx.x & 31;
    int g = threadIdx.x >> 5;   // 0..7
    float4 bv = ((const float4*)b2)[q];
    float sx = 0.f, sy = 0.f, sz = 0.f, sw = 0.f;  // running column sum
    for (int d = blockIdx.x * 8 + g; d < N; d += gridDim.x * 8) {
        int beg = rowptr[d], end = rowptr[d + 1];
        float ax = 0.f, ay = 0.f, az = 0.f, aw = 0.f;
        edge_accum(csr, beg, end, q, h, ax, ay, az, aw);
        float di = dinv[d], sl = di * di;
        uint2 hv = ((const uint2*)(h + (size_t)d * DIM))[q];
        sx += fmaxf(fmaf(__uint_as_float(hv.x << 16), sl, ax) + bv.x, 0.f);
        sy += fmaxf(fmaf(__uint_as_float(hv.x & 0xFFFF0000u), sl, ay) + bv.y, 0.f);
        sz += fmaxf(fmaf(__uint_as_float(hv.y << 16), sl, az) + bv.z, 0.f);
        sw += fmaxf(fmaf(__uint_as_float(hv.y & 0xFFFF0000u), sl, aw) + bv.w, 0.f);
    }
    __shared__ float4 sp[256];
    sp[threadIdx.x] = make_float4(sx, sy, sz, sw);
    __syncthreads();
    if (threadIdx.x < 32) {
        float4 s = sp[threadIdx.x];
        #pragma unroll
        for (int gg = 1; gg < 8; ++gg) {
            float4 o = sp[gg * 32 + threadIdx.x];
            s.x += o.x; s.y += o.y; s.z += o.z; s.w += o.w;
        }
        unsafeAtomicAdd(&meanacc[q * 4 + 0], s.x);
        unsafeAtomicAdd(&meanacc[q * 4 + 1], s.y);
        unsafeAtomicAdd(&meanacc[q * 4 + 2], s.z);
        unsafeAtomicAdd(&meanacc[q * 4 + 3], s.w);
    }
}

__global__ __launch_bounds__(DIM) void k_reduce(const float* __restrict__ meanacc,
                                                float* __restrict__ out, int N) {
    int j = threadIdx.x;
    out[DIM + j] = meanacc[j] / (float)N;
}

extern "C" void kernel_launch(void* const* d_in, const int* in_sizes, int n_in,
                              void* d_out, int out_size, void* d_ws, size_t ws_size,
                              hipStream_t stream) {
    const float* posts = (const float*)d_in[0];
    const int*   eidx  = (const int*)d_in[1];
    const int*   root  = (const int*)d_in[2];
    const float* W1    = (const float*)d_in[3];
    const float* b1    = (const float*)d_in[4];
    const float* W2    = (const float*)d_in[5];
    const float* b2    = (const float*)d_in[6];
    float* out = (float*)d_out;

    int N = in_sizes[0] / DIM;
    int E = in_sizes[1] / 2;
    const int* src = eidx;
    const int* dst = eidx + E;

    char* ws = (char*)d_ws;
    size_t off = 0;
    auto alloc = [&](size_t bytes) {
        void* p = ws + off;
        off += (bytes + 511) & ~(size_t)511;
        return p;
    };
    int*    deg     = (int*)   alloc((size_t)N * 4);
    int*    rowptr  = (int*)   alloc((size_t)(N + 1) * 4);
    int*    cursor  = (int*)   alloc((size_t)N * 4);
    float*  dinv    = (float*) alloc((size_t)N * 4);
    float*  cvec    = (float*) alloc(DIM * 4);
    float*  meanacc = (float*) alloc(DIM * 4);
    int2*   csr     = (int2*)  alloc((size_t)E * 8);
    ushort* h       = (ushort*)alloc((size_t)N * DIM * 2);   // bf16 h1, then h2
    float*  conv1   = (float*) alloc((size_t)N * DIM * 4);   // conv1_out (f32)

    hipMemsetAsync(deg, 0, (size_t)N * 4, stream);
    hipMemsetAsync(meanacc, 0, DIM * 4, stream);

    // CSR build (once, shared by both layers)
    k_count<<<(E + 255) / 256, 256, 0, stream>>>(dst, deg, E);
    k_scan<<<1, 1024, 0, stream>>>(deg, rowptr, cursor, N);
    k_dinv<<<(N + 255) / 256, 256, 0, stream>>>(deg, dinv, N);
    k_fill<<<(E + 255) / 256, 256, 0, stream>>>(src, dst, dinv, cursor, csr, E);

    // layer 1
    k_gemm<false, false><<<512, 256, 0, stream>>>(posts, W1, nullptr, h, N);
    k_gather1<<<2048, 256, 0, stream>>>(csr, rowptr, dinv, h, b1, root, conv1, out, N);

    // layer 2: h2 = cvec + relu(conv1) @ W2[128:], cvec = relu(post_root) @ W2[:128]
    k_cvec<<<1, DIM, 0, stream>>>(posts, root, W2, cvec);
    k_gemm<true, true><<<512, 256, 0, stream>>>(conv1, W2 + DIM * DIM, cvec, h, N);
    k_gather2<<<2048, 256, 0, stream>>>(csr, rowptr, dinv, h, b2, meanacc, N);
    k_reduce<<<1, DIM, 0, stream>>>(meanacc, out, N);
}